// Round 21
// baseline (161.929 us; speedup 1.0000x reference)
//
#include <hip/hip_runtime.h>
#include <hip/hip_fp16.h>

#define N_NODES 100000
#define N_EDGES 1600000
#define DIN 128
#define NH 4
#define ND 32
#define HD 128   // NH*ND
#define NEG_SLOPE 0.2f
#define MROWS 64       // gemm rows per block
#define APAD 136       // halves per LDS row (128 + 8 pad)
#define GEMM_BLOCKS ((N_NODES + MROWS - 1) / MROWS)   // 1563

// ---- bucket sort geometry ----
#define NBUCK 782      // ceil(N_NODES / 128) coarse buckets (dst>>7)
#define CHB 8192       // edges per hist/scatter block
#define NHB 196        // hist blocks: 196*8192 = 1,605,632 >= E
#define WCONV_BLOCKS 64

typedef _Float16 half8_t __attribute__((ext_vector_type(8)));
typedef float f32x4 __attribute__((ext_vector_type(4)));

__device__ __forceinline__ float lrelu(float x) {
    return x > 0.0f ? x : NEG_SLOPE * x;
}

union Pack8  { uint2 u; __half2 h2[2]; };
union Pack16 { uint4 u; __half2 h2[4]; };
union PackB  { uint4 u; half8_t h8; };

// ---------------- A: hist (blocks < NHB) | wconv (blocks >= NHB) ----------
__global__ __launch_bounds__(256) void k_histw(
    const int* __restrict__ dst, int* __restrict__ hist,
    const float* __restrict__ W, __half* __restrict__ Wt) {
    __shared__ int cnt[NBUCK];
    const int tid = threadIdx.x;

    if ((int)blockIdx.x >= NHB) {
        // wconv: W -> Wt fp16 transposed [c][k]
        int i = (blockIdx.x - NHB) * 256 + tid;   // 0..16383
        int k = i >> 7, c = i & 127;
        Wt[c * DIN + k] = __float2half(W[k * HD + c]);
        return;
    }
    if (!hist) return;
    for (int i = tid; i < NBUCK; i += 256) cnt[i] = 0;
    __syncthreads();
    int base = blockIdx.x * CHB;
#pragma unroll
    for (int j = 0; j < CHB / 256; ++j) {
        int e = base + j * 256 + tid;
        if (e < N_EDGES) atomicAdd(&cnt[dst[e] >> 7], 1);
    }
    __syncthreads();
    int* hrow = hist + (size_t)blockIdx.x * NBUCK;
    for (int i = tid; i < NBUCK; i += 256) hrow[i] = cnt[i];
}

// ---------------- B1: per-bucket column scan over NHB rows ----------------
__global__ __launch_bounds__(256) void k_scanH(int* __restrict__ hist,
                                               int* __restrict__ tot) {
    __shared__ int wtot[4];
    int b = blockIdx.x, tid = threadIdx.x;
    int v = (tid < NHB) ? hist[(size_t)tid * NBUCK + b] : 0;
    int lane = tid & 63, wv = tid >> 6;
    int incl = v;
#pragma unroll
    for (int off = 1; off < 64; off <<= 1) {
        int t = __shfl_up(incl, off, 64);
        if (lane >= off) incl += t;
    }
    if (lane == 63) wtot[wv] = incl;
    __syncthreads();
    int woff = 0;
    for (int w = 0; w < wv; ++w) woff += wtot[w];
    if (tid < NHB) hist[(size_t)tid * NBUCK + b] = woff + incl - v;
    if (tid == 0) tot[b] = wtot[0] + wtot[1] + wtot[2] + wtot[3];
}

// ---------------- B2: scan bucket totals -> bucket_base -------------------
__global__ __launch_bounds__(256) void k_scanT(const int* __restrict__ tot,
                                               int* __restrict__ bucket_base,
                                               int* __restrict__ rowptr) {
    __shared__ int wtot[4];
    int tid = threadIdx.x;
    int idx0 = tid * 4;
    int v[4];
#pragma unroll
    for (int j = 0; j < 4; ++j) {
        int b = idx0 + j;
        v[j] = (b < NBUCK) ? tot[b] : 0;
    }
    int s = v[0] + v[1] + v[2] + v[3];
    int lane = tid & 63;
    int incl = s;
#pragma unroll
    for (int off = 1; off < 64; off <<= 1) {
        int t = __shfl_up(incl, off, 64);
        if (lane >= off) incl += t;
    }
    if (lane == 63) wtot[tid >> 6] = incl;
    __syncthreads();
    int woff = 0;
    for (int w = 0; w < (tid >> 6); ++w) woff += wtot[w];
    int run = woff + incl - s;
#pragma unroll
    for (int j = 0; j < 4; ++j) {
        int b = idx0 + j;
        if (b < NBUCK) {
            int old = v[j];
            bucket_base[b] = run;
            run += old;
        }
    }
    if (tid == 0) {
        int total = wtot[0] + wtot[1] + wtot[2] + wtot[3];
        bucket_base[NBUCK] = total;
        rowptr[N_NODES] = total;
    }
}

// ---------------- C: cscat (blocks < NHB) | MFMA gemm (global-B) ----------
// B operands read directly from L2-hot Wt (32 KB) -> no Bs LDS, 17 KB LDS
// total -> 8 blocks/CU occupancy.
__global__ __launch_bounds__(256) void k_gemmcscat(
    const float* __restrict__ feat, const __half* __restrict__ Wt,
    const float* __restrict__ attn_l, const float* __restrict__ attn_r,
    __half* __restrict__ hhalf, float* __restrict__ el, float* __restrict__ er,
    const int* __restrict__ src, const int* __restrict__ dst,
    const int* __restrict__ hist, const int* __restrict__ bucket_base,
    int* __restrict__ bucketed) {

    __shared__ __align__(16) __half As[MROWS * APAD];  // 17408 B

    const int tid = threadIdx.x;

    if ((int)blockIdx.x < NHB) {
        // -------- coarse scatter: packed = src | (dst&127)<<17 --------
        if (!bucketed) return;
        int* cur = (int*)As;                  // 782 ints
        const int* hrow = hist + (size_t)blockIdx.x * NBUCK;
        for (int i = tid; i < NBUCK; i += 256) cur[i] = bucket_base[i] + hrow[i];
        __syncthreads();
        int base = blockIdx.x * CHB;
#pragma unroll
        for (int j = 0; j < CHB / 256; ++j) {
            int e = base + j * 256 + tid;
            if (e < N_EDGES) {
                int d = dst[e];
                int slot = atomicAdd(&cur[d >> 7], 1);
                bucketed[slot] = src[e] | ((d & 127) << 17);
            }
        }
        return;
    }

    // ---------------- gemm path ----------------
    const int row0 = (blockIdx.x - NHB) * MROWS;

    {   // stage feat -> As fp16
#pragma unroll
        for (int i = 0; i < 8; ++i) {
            int idx = tid + i * 256;
            int r = idx >> 5, c4 = idx & 31;
            int row = row0 + r;
            float4 f = (row < N_NODES)
                ? *(const float4*)(feat + (size_t)row * DIN + c4 * 4)
                : make_float4(0.0f, 0.0f, 0.0f, 0.0f);
            Pack8 pk;
            pk.h2[0] = __floats2half2_rn(f.x, f.y);
            pk.h2[1] = __floats2half2_rn(f.z, f.w);
            *(uint2*)(&As[r * APAD + c4 * 4]) = pk.u;
        }
    }
    __syncthreads();

    const int l = tid & 63;
    const int wv = tid >> 6;
    const int lrow = l & 15;
    const int kid = l >> 4;

    f32x4 acc[8];
#pragma unroll
    for (int n = 0; n < 8; ++n) acc[n] = (f32x4){0.0f, 0.0f, 0.0f, 0.0f};

#pragma unroll
    for (int kb = 0; kb < 4; ++kb) {
        half8_t a = *(const half8_t*)(&As[(wv * 16 + lrow) * APAD + kb * 32 + kid * 8]);
#pragma unroll
        for (int n = 0; n < 8; ++n) {
            PackB bv;
            bv.u = *(const uint4*)(Wt + (size_t)(n * 16 + lrow) * DIN + kb * 32 + kid * 8);
            acc[n] = __builtin_amdgcn_mfma_f32_16x16x32_f16(a, bv.h8, acc[n], 0, 0, 0);
        }
    }

    // ---- C -> LDS (reuse As) as fp16 [row][col] ----
    __syncthreads();
#pragma unroll
    for (int n = 0; n < 8; ++n)
#pragma unroll
        for (int r = 0; r < 4; ++r)
            As[(wv * 16 + kid * 4 + r) * APAD + n * 16 + lrow] =
                __float2half(acc[n][r]);
    __syncthreads();

    {   // epilogue: thread = (row = tid>>2, head = tid&3)
        int lr = tid >> 2;
        int row = row0 + lr;
        int head = tid & 3;
        if (row < N_NODES) {
            float suml = 0.0f, sumr = 0.0f;
#pragma unroll
            for (int q = 0; q < 4; ++q) {
                Pack16 p;
                p.u = *(const uint4*)(&As[lr * APAD + head * 32 + q * 8]);
                float4 al0 = *(const float4*)(attn_l + head * 32 + q * 8);
                float4 al1 = *(const float4*)(attn_l + head * 32 + q * 8 + 4);
                float4 ar0 = *(const float4*)(attn_r + head * 32 + q * 8);
                float4 ar1 = *(const float4*)(attn_r + head * 32 + q * 8 + 4);
                float2 x0 = __half22float2(p.h2[0]);
                float2 x1 = __half22float2(p.h2[1]);
                float2 x2 = __half22float2(p.h2[2]);
                float2 x3 = __half22float2(p.h2[3]);
                suml += x0.x * al0.x + x0.y * al0.y + x1.x * al0.z + x1.y * al0.w;
                suml += x2.x * al1.x + x2.y * al1.y + x3.x * al1.z + x3.y * al1.w;
                sumr += x0.x * ar0.x + x0.y * ar0.y + x1.x * ar0.z + x1.y * ar0.w;
                sumr += x2.x * ar1.x + x2.y * ar1.y + x3.x * ar1.z + x3.y * ar1.w;
                *(uint4*)(hhalf + (size_t)row * HD + head * 32 + q * 8) = p.u;
            }
            el[(size_t)row * NH + head] = suml;
            er[(size_t)row * NH + head] = sumr;
        }
    }
}

// ---------------- D: fine sort within bucket + rowptr ---------------------
__global__ __launch_bounds__(256) void k_fine(
    const int* __restrict__ bucketed, const int* __restrict__ bbase,
    int* __restrict__ srcs, int* __restrict__ rowptr) {

    __shared__ int cnt[128];
    __shared__ int noff[129];
    __shared__ int cur[128];

    const int b = blockIdx.x;
    const int tid = threadIdx.x;
    const int node0 = b << 7;
    const int beg = bbase[b], end = bbase[b + 1];

    if (tid < 128) cnt[tid] = 0;
    __syncthreads();

    for (int e = beg + tid; e < end; e += 256)
        atomicAdd(&cnt[bucketed[e] >> 17], 1);
    __syncthreads();

    // parallel 128-scan with wave 0 (2 elems/lane)
    if (tid < 64) {
        int v0 = cnt[tid * 2], v1 = cnt[tid * 2 + 1];
        int s = v0 + v1;
        int incl = s;
#pragma unroll
        for (int off = 1; off < 64; off <<= 1) {
            int t = __shfl_up(incl, off, 64);
            if (tid >= off) incl += t;
        }
        int excl = incl - s;
        noff[tid * 2] = excl;
        noff[tid * 2 + 1] = excl + v0;
        cur[tid * 2] = excl;
        cur[tid * 2 + 1] = excl + v0;
        if (tid == 63) noff[128] = incl;
    }
    __syncthreads();

    if (tid < 128) {
        int node = node0 + tid;
        if (node < N_NODES) rowptr[node] = beg + noff[tid];
    }

    for (int e = beg + tid; e < end; e += 256) {
        int p = bucketed[e];
        int d7 = p >> 17;
        int slot = beg + atomicAdd(&cur[d7], 1);
        srcs[slot] = p & 0x1FFFF;
    }
}

// ---------------- E: CSR gather-aggregate (single pass, 4-deep ILP) -------
__global__ __launch_bounds__(256) void k_agg_csr(
    const int* __restrict__ rowptr, const int* __restrict__ srcs,
    const float* __restrict__ el, const float* __restrict__ er,
    const __half* __restrict__ hhalf, float* __restrict__ out) {
    int node = blockIdx.x * 4 + (threadIdx.x >> 6);
    int lane = threadIdx.x & 63;
    int grp = lane >> 4;
    int cl = lane & 15;
    int head = cl >> 2;
    int beg = rowptr[node], end = rowptr[node + 1];

    const float er_h = er[(size_t)node * NH + head];

    float dsum = 0.0f;
    float a[8];
#pragma unroll
    for (int q = 0; q < 8; ++q) a[q] = 0.0f;

    int i = beg + grp;
    for (; i + 12 < end; i += 16) {
        int s0 = srcs[i], s1 = srcs[i + 4], s2 = srcs[i + 8], s3 = srcs[i + 12];
        float e0 = el[(size_t)s0 * NH + head];
        float e1 = el[(size_t)s1 * NH + head];
        float e2 = el[(size_t)s2 * NH + head];
        float e3 = el[(size_t)s3 * NH + head];
        Pack16 p0, p1, p2, p3;
        p0.u = *(const uint4*)(hhalf + (size_t)s0 * HD + cl * 8);
        p1.u = *(const uint4*)(hhalf + (size_t)s1 * HD + cl * 8);
        p2.u = *(const uint4*)(hhalf + (size_t)s2 * HD + cl * 8);
        p3.u = *(const uint4*)(hhalf + (size_t)s3 * HD + cl * 8);
        float w0 = __expf(lrelu(e0 + er_h));
        float w1 = __expf(lrelu(e1 + er_h));
        float w2 = __expf(lrelu(e2 + er_h));
        float w3 = __expf(lrelu(e3 + er_h));
        dsum += (w0 + w1) + (w2 + w3);
#pragma unroll
        for (int q = 0; q < 4; ++q) {
            float2 x0 = __half22float2(p0.h2[q]);
            float2 x1 = __half22float2(p1.h2[q]);
            float2 x2 = __half22float2(p2.h2[q]);
            float2 x3 = __half22float2(p3.h2[q]);
            a[2 * q]     = fmaf(x0.x, w0, a[2 * q]);
            a[2 * q + 1] = fmaf(x0.y, w0, a[2 * q + 1]);
            a[2 * q]     = fmaf(x1.x, w1, a[2 * q]);
            a[2 * q + 1] = fmaf(x1.y, w1, a[2 * q + 1]);
            a[2 * q]     = fmaf(x2.x, w2, a[2 * q]);
            a[2 * q + 1] = fmaf(x2.y, w2, a[2 * q + 1]);
            a[2 * q]     = fmaf(x3.x, w3, a[2 * q]);
            a[2 * q + 1] = fmaf(x3.y, w3, a[2 * q + 1]);
        }
    }
    for (; i + 4 < end; i += 8) {
        int s0 = srcs[i], s1 = srcs[i + 4];
        float e0 = el[(size_t)s0 * NH + head];
        float e1 = el[(size_t)s1 * NH + head];
        Pack16 p0, p1;
        p0.u = *(const uint4*)(hhalf + (size_t)s0 * HD + cl * 8);
        p1.u = *(const uint4*)(hhalf + (size_t)s1 * HD + cl * 8);
        float w0 = __expf(lrelu(e0 + er_h));
        float w1 = __expf(lrelu(e1 + er_h));
        dsum += w0 + w1;
#pragma unroll
        for (int q = 0; q < 4; ++q) {
            float2 x0 = __half22float2(p0.h2[q]);
            float2 x1 = __half22float2(p1.h2[q]);
            a[2 * q]     = fmaf(x0.x, w0, a[2 * q]);
            a[2 * q + 1] = fmaf(x0.y, w0, a[2 * q + 1]);
            a[2 * q]     = fmaf(x1.x, w1, a[2 * q]);
            a[2 * q + 1] = fmaf(x1.y, w1, a[2 * q + 1]);
        }
    }
    if (i < end) {
        int s0 = srcs[i];
        float w0 = __expf(lrelu(el[(size_t)s0 * NH + head] + er_h));
        Pack16 p0;
        p0.u = *(const uint4*)(hhalf + (size_t)s0 * HD + cl * 8);
        dsum += w0;
#pragma unroll
        for (int q = 0; q < 4; ++q) {
            float2 x0 = __half22float2(p0.h2[q]);
            a[2 * q]     = fmaf(x0.x, w0, a[2 * q]);
            a[2 * q + 1] = fmaf(x0.y, w0, a[2 * q + 1]);
        }
    }

    dsum += __shfl_xor(dsum, 16, 64);
    dsum += __shfl_xor(dsum, 32, 64);
#pragma unroll
    for (int q = 0; q < 8; ++q) {
        a[q] += __shfl_xor(a[q], 16, 64);
        a[q] += __shfl_xor(a[q], 32, 64);
    }

    if (grp == 0) {
        float inv = (end > beg) ? 1.0f / dsum : 0.0f;
        *(float4*)(out + (size_t)node * HD + cl * 8) =
            make_float4(a[0] * inv, a[1] * inv, a[2] * inv, a[3] * inv);
        *(float4*)(out + (size_t)node * HD + cl * 8 + 4) =
            make_float4(a[4] * inv, a[5] * inv, a[6] * inv, a[7] * inv);
    }
}

// ---------------- fallback path (atomics) --------------------------------
__global__ void k_init_fb(float* __restrict__ out, float* __restrict__ denom) {
    int i = blockIdx.x * blockDim.x + threadIdx.x;
    int stride = gridDim.x * blockDim.x;
    for (int j = i; j < N_NODES * HD; j += stride) out[j] = 0.0f;
    for (int j = i; j < N_NODES * NH; j += stride) denom[j] = 0.0f;
}

__global__ __launch_bounds__(256) void k_denom_fb(
    const int* __restrict__ src, const int* __restrict__ dst,
    const float* __restrict__ el, const float* __restrict__ er,
    float* __restrict__ denom) {
    int e = blockIdx.x * blockDim.x + threadIdx.x;
    if (e >= N_EDGES) return;
    int s = src[e], d = dst[e];
    float4 l = *(const float4*)(el + (size_t)s * NH);
    float4 r = *(const float4*)(er + (size_t)d * NH);
    float* dn = denom + (size_t)d * NH;
    atomicAdd(dn + 0, __expf(lrelu(l.x + r.x)));
    atomicAdd(dn + 1, __expf(lrelu(l.y + r.y)));
    atomicAdd(dn + 2, __expf(lrelu(l.z + r.z)));
    atomicAdd(dn + 3, __expf(lrelu(l.w + r.w)));
}

__global__ __launch_bounds__(256) void k_agg_fb(
    const int* __restrict__ src, const int* __restrict__ dst,
    const float* __restrict__ el, const float* __restrict__ er,
    const float* __restrict__ denom, const __half* __restrict__ hhalf,
    float* __restrict__ out) {
    long long t = (long long)blockIdx.x * blockDim.x + threadIdx.x;
    if (t >= (long long)N_EDGES * HD) return;
    int e = (int)(t >> 7);
    int c = (int)(t & 127);
    int hh = c >> 5;
    int s = src[e], d = dst[e];
    float x = lrelu(el[(size_t)s * NH + hh] + er[(size_t)d * NH + hh]);
    float a = __expf(x) / denom[(size_t)d * NH + hh];
    atomicAdd(out + (size_t)d * HD + c,
              __half2float(hhalf[(size_t)s * HD + c]) * a);
}

extern "C" void kernel_launch(void* const* d_in, const int* in_sizes, int n_in,
                              void* d_out, int out_size, void* d_ws, size_t ws_size,
                              hipStream_t stream) {
    const float* feat   = (const float*)d_in[0];
    const int*   src    = (const int*)d_in[1];
    const int*   dst    = (const int*)d_in[2];
    const float* W      = (const float*)d_in[3];
    const float* attn_l = (const float*)d_in[4];
    const float* attn_r = (const float*)d_in[5];
    float* out = (float*)d_out;

    char* base = (char*)d_ws;
    size_t off = 0;
    auto take = [&](size_t bytes) -> char* {
        char* r = base + off;
        off = (off + bytes + 255) & ~(size_t)255;
        return r;
    };
    __half* hhalf  = (__half*)take((size_t)N_NODES * HD * 2);
    float* el      = (float*)take((size_t)N_NODES * NH * 4);
    float* er      = (float*)take((size_t)N_NODES * NH * 4);
    __half* Wt     = (__half*)take((size_t)DIN * HD * 2);
    int*  hist     = (int*)take((size_t)NHB * NBUCK * 4);
    int*  tot      = (int*)take((size_t)NBUCK * 4);
    int*  bbase    = (int*)take((size_t)(NBUCK + 1) * 4);
    int*  bucketed = (int*)take((size_t)N_EDGES * 4);
    int*  srcs     = (int*)take((size_t)N_EDGES * 4);
    int*  rowptr   = (int*)take((size_t)(N_NODES + 1) * 4);
    float* denom   = (float*)take((size_t)N_NODES * NH * 4); // fallback only
    bool csr = (off <= ws_size);

    if (csr) {
        k_histw<<<NHB + WCONV_BLOCKS, 256, 0, stream>>>(dst, hist, W, Wt);
        k_scanH<<<NBUCK, 256, 0, stream>>>(hist, tot);
        k_scanT<<<1, 256, 0, stream>>>(tot, bbase, rowptr);
        k_gemmcscat<<<NHB + GEMM_BLOCKS, 256, 0, stream>>>(
            feat, Wt, attn_l, attn_r, hhalf, el, er,
            src, dst, hist, bbase, bucketed);
        k_fine<<<NBUCK, 256, 0, stream>>>(bucketed, bbase, srcs, rowptr);
        k_agg_csr<<<N_NODES / 4, 256, 0, stream>>>(rowptr, srcs, el, er,
                                                   hhalf, out);
    } else {
        int eb = (N_EDGES + 255) / 256;
        k_init_fb<<<2048, 256, 0, stream>>>(out, denom);
        k_histw<<<NHB + WCONV_BLOCKS, 256, 0, stream>>>(dst, (int*)nullptr,
                                                        W, Wt);
        k_gemmcscat<<<NHB + GEMM_BLOCKS, 256, 0, stream>>>(
            feat, Wt, attn_l, attn_r, hhalf, el, er,
            src, dst, (const int*)nullptr, (const int*)nullptr, (int*)nullptr);
        k_denom_fb<<<eb, 256, 0, stream>>>(src, dst, el, er, denom);
        long long totw = (long long)N_EDGES * HD;
        int ab = (int)((totw + 255) / 256);
        k_agg_fb<<<ab, 256, 0, stream>>>(src, dst, el, er, denom, hhalf, out);
    }
}

// Round 22
// 145.071 us; speedup vs baseline: 1.1162x; 1.1162x over previous
//
#include <hip/hip_runtime.h>
#include <hip/hip_fp16.h>

#define N_NODES 100000
#define N_EDGES 1600000
#define DIN 128
#define NH 4
#define ND 32
#define HD 128   // NH*ND
#define NEG_SLOPE 0.2f
#define MROWS 64       // gemm rows per block
#define APAD 136       // halves per LDS row (128 + 8 pad)
#define GEMM_BLOCKS ((N_NODES + MROWS - 1) / MROWS)   // 1563

// ---- bucket sort geometry ----
#define NBUCK 782      // ceil(N_NODES / 128) coarse buckets (dst>>7)
#define CHB 8192       // edges per hist/scatter block
#define NHB 196        // hist blocks: 196*8192 = 1,605,632 >= E
#define WCONV_BLOCKS 64

typedef _Float16 half8_t __attribute__((ext_vector_type(8)));
typedef float f32x4 __attribute__((ext_vector_type(4)));

__device__ __forceinline__ float lrelu(float x) {
    return x > 0.0f ? x : NEG_SLOPE * x;
}

union Pack8  { uint2 u; __half2 h2[2]; };
union Pack16 { uint4 u; __half2 h2[4]; };

// ---------------- A: hist (blocks < NHB) | wconv (blocks >= NHB) ----------
__global__ __launch_bounds__(256) void k_histw(
    const int* __restrict__ dst, int* __restrict__ hist,
    const float* __restrict__ W, __half* __restrict__ Wt) {
    __shared__ int cnt[NBUCK];
    const int tid = threadIdx.x;

    if ((int)blockIdx.x >= NHB) {
        // wconv: W -> Wt fp16 transposed [c][k]
        int i = (blockIdx.x - NHB) * 256 + tid;   // 0..16383
        int k = i >> 7, c = i & 127;
        Wt[c * DIN + k] = __float2half(W[k * HD + c]);
        return;
    }
    if (!hist) return;
    for (int i = tid; i < NBUCK; i += 256) cnt[i] = 0;
    __syncthreads();
    int base = blockIdx.x * CHB;
#pragma unroll
    for (int j = 0; j < CHB / 256; ++j) {
        int e = base + j * 256 + tid;
        if (e < N_EDGES) atomicAdd(&cnt[dst[e] >> 7], 1);
    }
    __syncthreads();
    int* hrow = hist + (size_t)blockIdx.x * NBUCK;
    for (int i = tid; i < NBUCK; i += 256) hrow[i] = cnt[i];
}

// ---------------- B1: per-bucket column scan over NHB rows ----------------
__global__ __launch_bounds__(256) void k_scanH(int* __restrict__ hist,
                                               int* __restrict__ tot) {
    __shared__ int wtot[4];
    int b = blockIdx.x, tid = threadIdx.x;
    int v = (tid < NHB) ? hist[(size_t)tid * NBUCK + b] : 0;
    int lane = tid & 63, wv = tid >> 6;
    int incl = v;
#pragma unroll
    for (int off = 1; off < 64; off <<= 1) {
        int t = __shfl_up(incl, off, 64);
        if (lane >= off) incl += t;
    }
    if (lane == 63) wtot[wv] = incl;
    __syncthreads();
    int woff = 0;
    for (int w = 0; w < wv; ++w) woff += wtot[w];
    if (tid < NHB) hist[(size_t)tid * NBUCK + b] = woff + incl - v;
    if (tid == 0) tot[b] = wtot[0] + wtot[1] + wtot[2] + wtot[3];
}

// ---------------- B2: scan bucket totals -> bucket_base -------------------
__global__ __launch_bounds__(256) void k_scanT(const int* __restrict__ tot,
                                               int* __restrict__ bucket_base,
                                               int* __restrict__ rowptr) {
    __shared__ int wtot[4];
    int tid = threadIdx.x;
    int idx0 = tid * 4;
    int v[4];
#pragma unroll
    for (int j = 0; j < 4; ++j) {
        int b = idx0 + j;
        v[j] = (b < NBUCK) ? tot[b] : 0;
    }
    int s = v[0] + v[1] + v[2] + v[3];
    int lane = tid & 63;
    int incl = s;
#pragma unroll
    for (int off = 1; off < 64; off <<= 1) {
        int t = __shfl_up(incl, off, 64);
        if (lane >= off) incl += t;
    }
    if (lane == 63) wtot[tid >> 6] = incl;
    __syncthreads();
    int woff = 0;
    for (int w = 0; w < (tid >> 6); ++w) woff += wtot[w];
    int run = woff + incl - s;
#pragma unroll
    for (int j = 0; j < 4; ++j) {
        int b = idx0 + j;
        if (b < NBUCK) {
            int old = v[j];
            bucket_base[b] = run;
            run += old;
        }
    }
    if (tid == 0) {
        int total = wtot[0] + wtot[1] + wtot[2] + wtot[3];
        bucket_base[NBUCK] = total;
        rowptr[N_NODES] = total;
    }
}

// ---------------- C: cscat (blocks < NHB, dispatched FIRST) | MFMA gemm ---
__global__ __launch_bounds__(256) void k_gemmcscat(
    const float* __restrict__ feat, const __half* __restrict__ Wt,
    const float* __restrict__ attn_l, const float* __restrict__ attn_r,
    __half* __restrict__ hhalf, float* __restrict__ el, float* __restrict__ er,
    const int* __restrict__ src, const int* __restrict__ dst,
    const int* __restrict__ hist, const int* __restrict__ bucket_base,
    int* __restrict__ bucketed) {

    __shared__ __align__(16) __half As[MROWS * APAD];  // 17408 B
    __shared__ __align__(16) __half Bs[HD * APAD];     // 34816 B

    const int tid = threadIdx.x;

    if ((int)blockIdx.x < NHB) {
        // -------- coarse scatter: packed = src | (dst&127)<<17 --------
        if (!bucketed) return;
        int* cur = (int*)As;                  // 782 ints
        const int* hrow = hist + (size_t)blockIdx.x * NBUCK;
        for (int i = tid; i < NBUCK; i += 256) cur[i] = bucket_base[i] + hrow[i];
        __syncthreads();
        int base = blockIdx.x * CHB;
#pragma unroll
        for (int j = 0; j < CHB / 256; ++j) {
            int e = base + j * 256 + tid;
            if (e < N_EDGES) {
                int d = dst[e];
                int slot = atomicAdd(&cur[d >> 7], 1);
                bucketed[slot] = src[e] | ((d & 127) << 17);
            }
        }
        return;
    }

    // ---------------- gemm path ----------------
    const int row0 = (blockIdx.x - NHB) * MROWS;

    {   // stage Wt -> Bs (2048 uint4)
        const uint4* Wv = (const uint4*)Wt;
#pragma unroll
        for (int i = 0; i < 8; ++i) {
            int idx = tid + i * 256;
            int c = idx >> 4, k8 = idx & 15;
            *(uint4*)(&Bs[c * APAD + k8 * 8]) = Wv[idx];
        }
    }
    {   // stage feat -> As fp16
#pragma unroll
        for (int i = 0; i < 8; ++i) {
            int idx = tid + i * 256;
            int r = idx >> 5, c4 = idx & 31;
            int row = row0 + r;
            float4 f = (row < N_NODES)
                ? *(const float4*)(feat + (size_t)row * DIN + c4 * 4)
                : make_float4(0.0f, 0.0f, 0.0f, 0.0f);
            Pack8 pk;
            pk.h2[0] = __floats2half2_rn(f.x, f.y);
            pk.h2[1] = __floats2half2_rn(f.z, f.w);
            *(uint2*)(&As[r * APAD + c4 * 4]) = pk.u;
        }
    }
    __syncthreads();

    const int l = tid & 63;
    const int wv = tid >> 6;
    const int lrow = l & 15;
    const int kid = l >> 4;

    f32x4 acc[8];
#pragma unroll
    for (int n = 0; n < 8; ++n) acc[n] = (f32x4){0.0f, 0.0f, 0.0f, 0.0f};

#pragma unroll
    for (int kb = 0; kb < 4; ++kb) {
        half8_t a = *(const half8_t*)(&As[(wv * 16 + lrow) * APAD + kb * 32 + kid * 8]);
#pragma unroll
        for (int n = 0; n < 8; ++n) {
            half8_t b = *(const half8_t*)(&Bs[(n * 16 + lrow) * APAD + kb * 32 + kid * 8]);
            acc[n] = __builtin_amdgcn_mfma_f32_16x16x32_f16(a, b, acc[n], 0, 0, 0);
        }
    }

    __syncthreads();
#pragma unroll
    for (int n = 0; n < 8; ++n)
#pragma unroll
        for (int r = 0; r < 4; ++r)
            As[(wv * 16 + kid * 4 + r) * APAD + n * 16 + lrow] =
                __float2half(acc[n][r]);
    __syncthreads();

    {   // epilogue: thread = (row = tid>>2, head = tid&3)
        int lr = tid >> 2;
        int row = row0 + lr;
        int head = tid & 3;
        if (row < N_NODES) {
            float suml = 0.0f, sumr = 0.0f;
#pragma unroll
            for (int q = 0; q < 4; ++q) {
                Pack16 p;
                p.u = *(const uint4*)(&As[lr * APAD + head * 32 + q * 8]);
                float4 al0 = *(const float4*)(attn_l + head * 32 + q * 8);
                float4 al1 = *(const float4*)(attn_l + head * 32 + q * 8 + 4);
                float4 ar0 = *(const float4*)(attn_r + head * 32 + q * 8);
                float4 ar1 = *(const float4*)(attn_r + head * 32 + q * 8 + 4);
                float2 x0 = __half22float2(p.h2[0]);
                float2 x1 = __half22float2(p.h2[1]);
                float2 x2 = __half22float2(p.h2[2]);
                float2 x3 = __half22float2(p.h2[3]);
                suml += x0.x * al0.x + x0.y * al0.y + x1.x * al0.z + x1.y * al0.w;
                suml += x2.x * al1.x + x2.y * al1.y + x3.x * al1.z + x3.y * al1.w;
                sumr += x0.x * ar0.x + x0.y * ar0.y + x1.x * ar0.z + x1.y * ar0.w;
                sumr += x2.x * ar1.x + x2.y * ar1.y + x3.x * ar1.z + x3.y * ar1.w;
                *(uint4*)(hhalf + (size_t)row * HD + head * 32 + q * 8) = p.u;
            }
            el[(size_t)row * NH + head] = suml;
            er[(size_t)row * NH + head] = sumr;
        }
    }
}

// ---------------- D: fine sort within bucket + rowptr (512 threads) -------
__global__ __launch_bounds__(512) void k_fine(
    const int* __restrict__ bucketed, const int* __restrict__ bbase,
    int* __restrict__ srcs, int* __restrict__ rowptr) {

    __shared__ int cnt[128];
    __shared__ int noff[129];
    __shared__ int cur[128];

    const int b = blockIdx.x;
    const int tid = threadIdx.x;
    const int node0 = b << 7;
    const int beg = bbase[b], end = bbase[b + 1];

    if (tid < 128) cnt[tid] = 0;
    __syncthreads();

    for (int e = beg + tid; e < end; e += 512)
        atomicAdd(&cnt[bucketed[e] >> 17], 1);
    __syncthreads();

    // parallel 128-scan with wave 0 (2 elems/lane)
    if (tid < 64) {
        int v0 = cnt[tid * 2], v1 = cnt[tid * 2 + 1];
        int s = v0 + v1;
        int incl = s;
#pragma unroll
        for (int off = 1; off < 64; off <<= 1) {
            int t = __shfl_up(incl, off, 64);
            if (tid >= off) incl += t;
        }
        int excl = incl - s;
        noff[tid * 2] = excl;
        noff[tid * 2 + 1] = excl + v0;
        cur[tid * 2] = excl;
        cur[tid * 2 + 1] = excl + v0;
        if (tid == 63) noff[128] = incl;
    }
    __syncthreads();

    if (tid < 128) {
        int node = node0 + tid;
        if (node < N_NODES) rowptr[node] = beg + noff[tid];
    }

    for (int e = beg + tid; e < end; e += 512) {
        int p = bucketed[e];
        int d7 = p >> 17;
        int slot = beg + atomicAdd(&cur[d7], 1);
        srcs[slot] = p & 0x1FFFF;
    }
}

// ---------------- E: CSR gather-aggregate (single pass, 4-deep ILP) -------
__global__ __launch_bounds__(256) void k_agg_csr(
    const int* __restrict__ rowptr, const int* __restrict__ srcs,
    const float* __restrict__ el, const float* __restrict__ er,
    const __half* __restrict__ hhalf, float* __restrict__ out) {
    int node = blockIdx.x * 4 + (threadIdx.x >> 6);
    int lane = threadIdx.x & 63;
    int grp = lane >> 4;
    int cl = lane & 15;
    int head = cl >> 2;
    int beg = rowptr[node], end = rowptr[node + 1];

    const float er_h = er[(size_t)node * NH + head];

    float dsum = 0.0f;
    float a[8];
#pragma unroll
    for (int q = 0; q < 8; ++q) a[q] = 0.0f;

    int i = beg + grp;
    for (; i + 12 < end; i += 16) {
        int s0 = srcs[i], s1 = srcs[i + 4], s2 = srcs[i + 8], s3 = srcs[i + 12];
        float e0 = el[(size_t)s0 * NH + head];
        float e1 = el[(size_t)s1 * NH + head];
        float e2 = el[(size_t)s2 * NH + head];
        float e3 = el[(size_t)s3 * NH + head];
        Pack16 p0, p1, p2, p3;
        p0.u = *(const uint4*)(hhalf + (size_t)s0 * HD + cl * 8);
        p1.u = *(const uint4*)(hhalf + (size_t)s1 * HD + cl * 8);
        p2.u = *(const uint4*)(hhalf + (size_t)s2 * HD + cl * 8);
        p3.u = *(const uint4*)(hhalf + (size_t)s3 * HD + cl * 8);
        float w0 = __expf(lrelu(e0 + er_h));
        float w1 = __expf(lrelu(e1 + er_h));
        float w2 = __expf(lrelu(e2 + er_h));
        float w3 = __expf(lrelu(e3 + er_h));
        dsum += (w0 + w1) + (w2 + w3);
#pragma unroll
        for (int q = 0; q < 4; ++q) {
            float2 x0 = __half22float2(p0.h2[q]);
            float2 x1 = __half22float2(p1.h2[q]);
            float2 x2 = __half22float2(p2.h2[q]);
            float2 x3 = __half22float2(p3.h2[q]);
            a[2 * q]     = fmaf(x0.x, w0, a[2 * q]);
            a[2 * q + 1] = fmaf(x0.y, w0, a[2 * q + 1]);
            a[2 * q]     = fmaf(x1.x, w1, a[2 * q]);
            a[2 * q + 1] = fmaf(x1.y, w1, a[2 * q + 1]);
            a[2 * q]     = fmaf(x2.x, w2, a[2 * q]);
            a[2 * q + 1] = fmaf(x2.y, w2, a[2 * q + 1]);
            a[2 * q]     = fmaf(x3.x, w3, a[2 * q]);
            a[2 * q + 1] = fmaf(x3.y, w3, a[2 * q + 1]);
        }
    }
    for (; i + 4 < end; i += 8) {
        int s0 = srcs[i], s1 = srcs[i + 4];
        float e0 = el[(size_t)s0 * NH + head];
        float e1 = el[(size_t)s1 * NH + head];
        Pack16 p0, p1;
        p0.u = *(const uint4*)(hhalf + (size_t)s0 * HD + cl * 8);
        p1.u = *(const uint4*)(hhalf + (size_t)s1 * HD + cl * 8);
        float w0 = __expf(lrelu(e0 + er_h));
        float w1 = __expf(lrelu(e1 + er_h));
        dsum += w0 + w1;
#pragma unroll
        for (int q = 0; q < 4; ++q) {
            float2 x0 = __half22float2(p0.h2[q]);
            float2 x1 = __half22float2(p1.h2[q]);
            a[2 * q]     = fmaf(x0.x, w0, a[2 * q]);
            a[2 * q + 1] = fmaf(x0.y, w0, a[2 * q + 1]);
            a[2 * q]     = fmaf(x1.x, w1, a[2 * q]);
            a[2 * q + 1] = fmaf(x1.y, w1, a[2 * q + 1]);
        }
    }
    if (i < end) {
        int s0 = srcs[i];
        float w0 = __expf(lrelu(el[(size_t)s0 * NH + head] + er_h));
        Pack16 p0;
        p0.u = *(const uint4*)(hhalf + (size_t)s0 * HD + cl * 8);
        dsum += w0;
#pragma unroll
        for (int q = 0; q < 4; ++q) {
            float2 x0 = __half22float2(p0.h2[q]);
            a[2 * q]     = fmaf(x0.x, w0, a[2 * q]);
            a[2 * q + 1] = fmaf(x0.y, w0, a[2 * q + 1]);
        }
    }

    dsum += __shfl_xor(dsum, 16, 64);
    dsum += __shfl_xor(dsum, 32, 64);
#pragma unroll
    for (int q = 0; q < 8; ++q) {
        a[q] += __shfl_xor(a[q], 16, 64);
        a[q] += __shfl_xor(a[q], 32, 64);
    }

    if (grp == 0) {
        float inv = (end > beg) ? 1.0f / dsum : 0.0f;
        *(float4*)(out + (size_t)node * HD + cl * 8) =
            make_float4(a[0] * inv, a[1] * inv, a[2] * inv, a[3] * inv);
        *(float4*)(out + (size_t)node * HD + cl * 8 + 4) =
            make_float4(a[4] * inv, a[5] * inv, a[6] * inv, a[7] * inv);
    }
}

// ---------------- fallback path (atomics) --------------------------------
__global__ void k_init_fb(float* __restrict__ out, float* __restrict__ denom) {
    int i = blockIdx.x * blockDim.x + threadIdx.x;
    int stride = gridDim.x * blockDim.x;
    for (int j = i; j < N_NODES * HD; j += stride) out[j] = 0.0f;
    for (int j = i; j < N_NODES * NH; j += stride) denom[j] = 0.0f;
}

__global__ __launch_bounds__(256) void k_denom_fb(
    const int* __restrict__ src, const int* __restrict__ dst,
    const float* __restrict__ el, const float* __restrict__ er,
    float* __restrict__ denom) {
    int e = blockIdx.x * blockDim.x + threadIdx.x;
    if (e >= N_EDGES) return;
    int s = src[e], d = dst[e];
    float4 l = *(const float4*)(el + (size_t)s * NH);
    float4 r = *(const float4*)(er + (size_t)d * NH);
    float* dn = denom + (size_t)d * NH;
    atomicAdd(dn + 0, __expf(lrelu(l.x + r.x)));
    atomicAdd(dn + 1, __expf(lrelu(l.y + r.y)));
    atomicAdd(dn + 2, __expf(lrelu(l.z + r.z)));
    atomicAdd(dn + 3, __expf(lrelu(l.w + r.w)));
}

__global__ __launch_bounds__(256) void k_agg_fb(
    const int* __restrict__ src, const int* __restrict__ dst,
    const float* __restrict__ el, const float* __restrict__ er,
    const float* __restrict__ denom, const __half* __restrict__ hhalf,
    float* __restrict__ out) {
    long long t = (long long)blockIdx.x * blockDim.x + threadIdx.x;
    if (t >= (long long)N_EDGES * HD) return;
    int e = (int)(t >> 7);
    int c = (int)(t & 127);
    int hh = c >> 5;
    int s = src[e], d = dst[e];
    float x = lrelu(el[(size_t)s * NH + hh] + er[(size_t)d * NH + hh]);
    float a = __expf(x) / denom[(size_t)d * NH + hh];
    atomicAdd(out + (size_t)d * HD + c,
              __half2float(hhalf[(size_t)s * HD + c]) * a);
}

extern "C" void kernel_launch(void* const* d_in, const int* in_sizes, int n_in,
                              void* d_out, int out_size, void* d_ws, size_t ws_size,
                              hipStream_t stream) {
    const float* feat   = (const float*)d_in[0];
    const int*   src    = (const int*)d_in[1];
    const int*   dst    = (const int*)d_in[2];
    const float* W      = (const float*)d_in[3];
    const float* attn_l = (const float*)d_in[4];
    const float* attn_r = (const float*)d_in[5];
    float* out = (float*)d_out;

    char* base = (char*)d_ws;
    size_t off = 0;
    auto take = [&](size_t bytes) -> char* {
        char* r = base + off;
        off = (off + bytes + 255) & ~(size_t)255;
        return r;
    };
    __half* hhalf  = (__half*)take((size_t)N_NODES * HD * 2);
    float* el      = (float*)take((size_t)N_NODES * NH * 4);
    float* er      = (float*)take((size_t)N_NODES * NH * 4);
    __half* Wt     = (__half*)take((size_t)DIN * HD * 2);
    int*  hist     = (int*)take((size_t)NHB * NBUCK * 4);
    int*  tot      = (int*)take((size_t)NBUCK * 4);
    int*  bbase    = (int*)take((size_t)(NBUCK + 1) * 4);
    int*  bucketed = (int*)take((size_t)N_EDGES * 4);
    int*  srcs     = (int*)take((size_t)N_EDGES * 4);
    int*  rowptr   = (int*)take((size_t)(N_NODES + 1) * 4);
    float* denom   = (float*)take((size_t)N_NODES * NH * 4); // fallback only
    bool csr = (off <= ws_size);

    if (csr) {
        k_histw<<<NHB + WCONV_BLOCKS, 256, 0, stream>>>(dst, hist, W, Wt);
        k_scanH<<<NBUCK, 256, 0, stream>>>(hist, tot);
        k_scanT<<<1, 256, 0, stream>>>(tot, bbase, rowptr);
        k_gemmcscat<<<NHB + GEMM_BLOCKS, 256, 0, stream>>>(
            feat, Wt, attn_l, attn_r, hhalf, el, er,
            src, dst, hist, bbase, bucketed);
        k_fine<<<NBUCK, 512, 0, stream>>>(bucketed, bbase, srcs, rowptr);
        k_agg_csr<<<N_NODES / 4, 256, 0, stream>>>(rowptr, srcs, el, er,
                                                   hhalf, out);
    } else {
        int eb = (N_EDGES + 255) / 256;
        k_init_fb<<<2048, 256, 0, stream>>>(out, denom);
        k_histw<<<NHB + WCONV_BLOCKS, 256, 0, stream>>>(dst, (int*)nullptr,
                                                        W, Wt);
        k_gemmcscat<<<NHB + GEMM_BLOCKS, 256, 0, stream>>>(
            feat, Wt, attn_l, attn_r, hhalf, el, er,
            src, dst, (const int*)nullptr, (const int*)nullptr, (int*)nullptr);
        k_denom_fb<<<eb, 256, 0, stream>>>(src, dst, el, er, denom);
        long long totw = (long long)N_EDGES * HD;
        int ab = (int)((totw + 255) / 256);
        k_agg_fb<<<ab, 256, 0, stream>>>(src, dst, el, er, denom, hhalf, out);
    }
}